// Round 14
// baseline (156.796 us; speedup 1.0000x reference)
//
#include <hip/hip_runtime.h>
#include <hip/hip_bf16.h>

#define Bq 64
#define Sq 256
#define Dq 768
#define CAPq 8
#define NTq 10
#define SCq 2048   // S*CAP

typedef short bf16x8 __attribute__((ext_vector_type(8)));
typedef float f32x4  __attribute__((ext_vector_type(4)));

// split f32 into hi/lo bf16 (bit-truncation; f ~= hi + lo, residual ~2^-17 |f|)
static __device__ __forceinline__ short bfhi(float f) {
    return (short)(__float_as_uint(f) >> 16);
}
static __device__ __forceinline__ short bflo(float f) {
    float hi = __uint_as_float(__float_as_uint(f) & 0xFFFF0000u);
    return (short)(__float_as_uint(f - hi) >> 16);
}

// ---------------- Kernel 0: preconvert fc1w (80x768 f32, [n*8+c][k]) into
// fragment-major hi/lo bf16: fw2[k/8][col=80][8], col = n*8+c.
__global__ __launch_bounds__(256) void k0_cvt(const float* __restrict__ w,
                                              short* __restrict__ hi,
                                              short* __restrict__ lo) {
    int i = blockIdx.x * 256 + threadIdx.x;   // output index
    if (i < NTq * CAPq * Dq) {
        int k8 = i / 640;
        int rem = i - k8 * 640;
        int o = rem >> 3, kf = rem & 7;
        float f = w[o * Dq + k8 * 8 + kf];
        hi[i] = bfhi(f);
        lo[i] = bflo(f);
    }
}

// ---------------- Kernel 1 (split-bf16 MFMA, LDS-staged x): sem = x·fc1w^T + b,
// squash over routes, write u2 hi/lo bf16, layout [n][s][b][c].
__global__ __launch_bounds__(256) void k1_sem(const float* __restrict__ x,
                                              const short* __restrict__ fwh,
                                              const short* __restrict__ fwl,
                                              const float* __restrict__ fc1b,
                                              short* __restrict__ u_hi,
                                              short* __restrict__ u_lo) {
    __shared__ short xsh[12288];   // [k8=96][row=16][8] hi   (24 KB)
    __shared__ short xsl[12288];   // lo                      (24 KB)
    const int t = threadIdx.x;
    const int L = t & 63, w = t >> 6;          // w = k-part 0..3
    const int colL = L & 15, kg = L >> 4;
    const int R0 = blockIdx.x * 16;

    // ---- stage x[R0..R0+15][0..767] -> LDS hi/lo, coalesced
    const float* xbase = x + (size_t)R0 * Dq;
#pragma unroll
    for (int i = 0; i < 12; ++i) {
        int li = t + i * 256;                  // float4 index, 0..3071
        int r = li / 192, j = li - r * 192;    // row, float4-within-row
        float4 v = *reinterpret_cast<const float4*>(xbase + (size_t)r * Dq + j * 4);
        int k8 = j >> 1, kf = (j & 1) * 4;
        int off = (k8 * 16 + r) * 8 + kf;
        short4 h4, l4;
        h4.x = bfhi(v.x); h4.y = bfhi(v.y); h4.z = bfhi(v.z); h4.w = bfhi(v.w);
        l4.x = bflo(v.x); l4.y = bflo(v.y); l4.z = bflo(v.z); l4.w = bflo(v.w);
        *reinterpret_cast<short4*>(&xsh[off]) = h4;
        *reinterpret_cast<short4*>(&xsl[off]) = l4;
    }
    __syncthreads();

    f32x4 acc[5];
#pragma unroll
    for (int f = 0; f < 5; ++f) acc[f] = (f32x4){0.f, 0.f, 0.f, 0.f};

    const short* pwh = fwh + kg * 640 + colL * 8;
    const short* pwl = fwl + kg * 640 + colL * 8;

#pragma unroll 2
    for (int kc = 0; kc < 192; kc += 32) {
        const int k8 = ((w * 192 + kc) >> 3) + kg;
        bf16x8 ah = *reinterpret_cast<const bf16x8*>(&xsh[(k8 * 16 + colL) * 8]);
        bf16x8 al = *reinterpret_cast<const bf16x8*>(&xsl[(k8 * 16 + colL) * 8]);
        const int ko80 = (w * 192 + kc) * 80;
#pragma unroll
        for (int f = 0; f < 5; ++f) {
            bf16x8 bh = *reinterpret_cast<const bf16x8*>(pwh + ko80 + f * 128);
            bf16x8 bl = *reinterpret_cast<const bf16x8*>(pwl + ko80 + f * 128);
            acc[f] = __builtin_amdgcn_mfma_f32_16x16x32_bf16(al, bh, acc[f], 0, 0, 0);
            acc[f] = __builtin_amdgcn_mfma_f32_16x16x32_bf16(ah, bl, acc[f], 0, 0, 0);
            acc[f] = __builtin_amdgcn_mfma_f32_16x16x32_bf16(ah, bh, acc[f], 0, 0, 0);
        }
    }

    // ---- 4-way k-reduce: redS overlaid on xsh (all waves done reading xs)
    float* redS = reinterpret_cast<float*>(xsh);   // [3][20][64] floats
    __syncthreads();
    if (w > 0) {
#pragma unroll
        for (int f = 0; f < 5; ++f)
#pragma unroll
            for (int g = 0; g < 4; ++g)
                redS[((w - 1) * 20 + f * 4 + g) * 64 + L] = acc[f][g];
    }
    __syncthreads();
    if (w == 0) {
        float bias[5];
#pragma unroll
        for (int f = 0; f < 5; ++f) bias[f] = fc1b[f * 16 + colL];
        const int cc = colL & 7;
        const int npar = (colL >> 3) & 1;
#pragma unroll
        for (int reg = 0; reg < 4; ++reg) {
            const int row = R0 + kg * 4 + reg;             // C/D: row=(L>>4)*4+reg
            const int b = row >> 8, s = row & 255;
            float v[5], sqp = 0.f;
#pragma unroll
            for (int f = 0; f < 5; ++f) {
                v[f] = acc[f][reg] + redS[(0 * 20 + f * 4 + reg) * 64 + L]
                     + redS[(1 * 20 + f * 4 + reg) * 64 + L]
                     + redS[(2 * 20 + f * 4 + reg) * 64 + L] + bias[f];
                sqp = fmaf(v[f], v[f], sqp);
            }
            float sq = sqp + __shfl_xor(sqp, 8, 64);       // pair even/odd routes (colL ^ 8)
            float scale = (sq / (1.f + sq)) / sqrtf(sq);
#pragma unroll
            for (int f = 0; f < 5; ++f) {
                int n = 2 * f + npar;
                size_t off = (((size_t)n * 256 + s) * 64 + b) * 8 + cc;   // u2[n][s][b][c]
                float val = v[f] * scale;
                u_hi[off] = bfhi(val);
                u_lo[off] = bflo(val);
            }
        }
    }
}

// ---------------- Kernel 2 (split-bf16 MFMA, LDS-staged rw, raw-barrier async pipeline):
// part[ks][c][b][r][l] = sum_{k in half ks} u[b,r,k]*rw[c,r,k,l]
__global__ __launch_bounds__(256) void k2_priors(const short* __restrict__ u_hi,
                                                 const short* __restrict__ u_lo,
                                                 const float* __restrict__ rw,
                                                 const int* __restrict__ task_p,
                                                 float* __restrict__ part) {
    const int bid = blockIdx.x;
    const int lq = bid / 160;
    const int rem = bid - lq * 160;          // ks + 2*(r + 10*c)
    const int ks = rem & 1;
    const int rc = rem >> 1;                 // r + 10*c
    const int c = rc / 10;
    const int r = rc - c * 10;
    if (r > *task_p) return;
    __shared__ __attribute__((aligned(16))) float ldsb[2048];   // 2 x [32k][32l] f32
    const int t0 = threadIdx.x;
    const int L = t0 & 63, w = t0 >> 6;
    const int colL = L & 15, kg = L >> 4;
    const int kw0 = ks * 1024;
    const int s00 = ks * 128;

    f32x4 accE = (f32x4){0.f, 0.f, 0.f, 0.f};
    f32x4 accO = (f32x4){0.f, 0.f, 0.f, 0.f};

    const float* psrc = rw + (((size_t)(c * NTq + r)) * SCq + kw0 + w * 8 + (L >> 3)) * Sq
                           + lq * 32 + (L & 7) * 4;
    const short* puh = u_hi + (((size_t)r * 256 + s00 + kg) * 64 + w * 16 + colL) * 8;
    const short* pul = u_lo + (((size_t)r * 256 + s00 + kg) * 64 + w * 16 + colL) * 8;

    float4 stg = *reinterpret_cast<const float4*>(psrc);     // prologue: chunk 0

    for (int t = 0; t < 32; ++t) {
        float* dst = &ldsb[(t & 1) * 1024 + w * 256 + L * 4];
        *reinterpret_cast<float4*>(dst) = stg;
        asm volatile("s_waitcnt lgkmcnt(0)" ::: "memory");
        __builtin_amdgcn_sched_barrier(0);
        __builtin_amdgcn_s_barrier();                        // NO vmcnt drain here
        __builtin_amdgcn_sched_barrier(0);
        bf16x8 ah = *reinterpret_cast<const bf16x8*>(puh + (size_t)t * 2048);
        bf16x8 al = *reinterpret_cast<const bf16x8*>(pul + (size_t)t * 2048);
        __builtin_amdgcn_sched_barrier(0);
        if (t + 1 < 32)
            stg = *reinterpret_cast<const float4*>(psrc + (size_t)(t + 1) * 8192);
        __builtin_amdgcn_sched_barrier(0);
        const float* lbp = &ldsb[(t & 1) * 1024 + colL * 2];
        float2 bv[8];
#pragma unroll
        for (int j = 0; j < 8; ++j)
            bv[j] = *reinterpret_cast<const float2*>(lbp + (kg * 8 + j) * 32);
        bf16x8 bhE, blE, bhO, blO;
#pragma unroll
        for (int j = 0; j < 8; ++j) {
            bhE[j] = bfhi(bv[j].x); blE[j] = bflo(bv[j].x);
            bhO[j] = bfhi(bv[j].y); blO[j] = bflo(bv[j].y);
        }
        accE = __builtin_amdgcn_mfma_f32_16x16x32_bf16(al, bhE, accE, 0, 0, 0);
        accE = __builtin_amdgcn_mfma_f32_16x16x32_bf16(ah, blE, accE, 0, 0, 0);
        accE = __builtin_amdgcn_mfma_f32_16x16x32_bf16(ah, bhE, accE, 0, 0, 0);
        accO = __builtin_amdgcn_mfma_f32_16x16x32_bf16(al, bhO, accO, 0, 0, 0);
        accO = __builtin_amdgcn_mfma_f32_16x16x32_bf16(ah, blO, accO, 0, 0, 0);
        accO = __builtin_amdgcn_mfma_f32_16x16x32_bf16(ah, bhO, accO, 0, 0, 0);
    }

    const int le = lq * 32 + 2 * colL;
#pragma unroll
    for (int g = 0; g < 4; ++g) {
        int bb = w * 16 + kg * 4 + g;
        size_t idx = (size_t)ks * 1310720 + ((size_t)(c * Bq + bb) * NTq + r) * Sq + le;
        float2 vv; vv.x = accE[g]; vv.y = accO[g];
        *reinterpret_cast<float2*>(part + idx) = vv;
    }
}

// ---------------- Kernel 3+4 fused: routing per (c,b) + direct output projection.
__global__ __launch_bounds__(256) void k34_route_out(const float* __restrict__ part,
                                                     const int* __restrict__ task_p,
                                                     const float* __restrict__ lw,   // [768][8]
                                                     const float* __restrict__ lb,   // [768]
                                                     float* __restrict__ out) {      // [B,S,768]
    const int t = threadIdx.x;
    const int lane = t & 63, w = t >> 6;
    const int b = blockIdx.x & 63, c = blockIdx.x >> 6;
    const int task = *task_p;

    float pr[NTq][4];
    const float* p0 = part + ((size_t)(c * Bq + b) * NTq) * Sq + lane * 4;
#pragma unroll
    for (int r = 0; r < NTq; ++r) {
        f32x4 a = *reinterpret_cast<const f32x4*>(p0 + r * Sq);
        f32x4 d = *reinterpret_cast<const f32x4*>(p0 + 1310720 + r * Sq);
#pragma unroll
        for (int ii = 0; ii < 4; ++ii) pr[r][ii] = a[ii] + d[ii];
    }

    float logits[NTq];
#pragma unroll
    for (int r = 0; r < NTq; ++r) logits[r] = 0.f;
    float vote[4];

    for (int it = 0; it < 3; ++it) {
        float m = -1e30f;
#pragma unroll
        for (int r = 0; r < NTq; ++r) if (r <= task) m = fmaxf(m, logits[r]);
        float p[NTq]; float s = 0.f;
#pragma unroll
        for (int r = 0; r < NTq; ++r) {
            p[r] = (r <= task) ? expf(logits[r] - m) : 0.f;
            s += p[r];
        }
        float inv = 1.f / s;
#pragma unroll
        for (int ii = 0; ii < 4; ++ii) vote[ii] = 0.f;
#pragma unroll
        for (int r = 0; r < NTq; ++r) {
            float pw = p[r] * inv;
#pragma unroll
            for (int ii = 0; ii < 4; ++ii) vote[ii] = fmaf(pw, pr[r][ii], vote[ii]);
        }
        if (it == 2) break;

        float vals[11];
#pragma unroll
        for (int r = 0; r < NTq; ++r) {
            float d = 0.f;
#pragma unroll
            for (int ii = 0; ii < 4; ++ii) d = fmaf(pr[r][ii], vote[ii], d);
            vals[r] = d;
        }
        {
            float d = 0.f;
#pragma unroll
            for (int ii = 0; ii < 4; ++ii) d = fmaf(vote[ii], vote[ii], d);
            vals[10] = d;
        }
#pragma unroll
        for (int o = 32; o > 0; o >>= 1) {
#pragma unroll
            for (int v = 0; v < 11; ++v) vals[v] += __shfl_xor(vals[v], o, 64);
        }
        float sq = vals[10];
        float scale = (sq / (1.f + sq)) / sqrtf(sq);
#pragma unroll
        for (int r = 0; r < NTq; ++r)
            if (r <= task) logits[r] += scale * vals[r];
    }

    // ---- epilogue: wave w writes out rows rbase..rbase+7
    float v[8][8];
#pragma unroll
    for (int j = 0; j < 8; ++j) {
        int s0 = w * 16 + 2 * j;
#pragma unroll
        for (int ii = 0; ii < 4; ++ii) v[j][ii]     = __shfl(vote[ii], s0, 64);
#pragma unroll
        for (int ii = 0; ii < 4; ++ii) v[j][4 + ii] = __shfl(vote[ii], s0 + 1, 64);
    }
    const int rbase = c * 2048 + b * 32 + w * 8;
#pragma unroll
    for (int dd = 0; dd < 12; ++dd) {
        int d = lane + dd * 64;
        float4 wa = *reinterpret_cast<const float4*>(lw + (size_t)d * 8);
        float4 wb = *reinterpret_cast<const float4*>(lw + (size_t)d * 8 + 4);
        float lbv = lb[d];
#pragma unroll
        for (int j = 0; j < 8; ++j) {
            float acc = lbv;
            acc = fmaf(v[j][0], wa.x, acc);
            acc = fmaf(v[j][1], wa.y, acc);
            acc = fmaf(v[j][2], wa.z, acc);
            acc = fmaf(v[j][3], wa.w, acc);
            acc = fmaf(v[j][4], wb.x, acc);
            acc = fmaf(v[j][5], wb.y, acc);
            acc = fmaf(v[j][6], wb.z, acc);
            acc = fmaf(v[j][7], wb.w, acc);
            out[(size_t)(rbase + j) * Dq + d] = acc;
        }
    }
}

extern "C" void kernel_launch(void* const* d_in, const int* in_sizes, int n_in,
                              void* d_out, int out_size, void* d_ws, size_t ws_size,
                              hipStream_t stream) {
    const float* x    = (const float*)d_in[0];
    const int*   task = (const int*)d_in[1];
    const float* fc1w = (const float*)d_in[2];
    const float* fc1b = (const float*)d_in[3];
    const float* rw   = (const float*)d_in[4];
    const float* lw   = (const float*)d_in[5];
    const float* lb   = (const float*)d_in[6];
    float* out = (float*)d_out;

    short* u_hi = (short*)d_ws;                              // 2,621,440 B
    short* u_lo = u_hi + 1310720;                            // 2,621,440 B
    float* part = (float*)((char*)d_ws + 5242880);           // 10,485,760 B
    short* fwh  = (short*)((char*)d_ws + 16252928);          // 122,880 B
    short* fwl  = fwh + 61440;                               // 122,880 B

    // ATTRIBUTION ROUND (kernels byte-identical to R13; only launch counts differ):
    //   k1 x3 and k34 x3 (both idempotent), k2 x1.
    //   R14 - R13 = 2*k1 + 2*k34 - k2(warm) + 3*gap
    //   -> k1 + k34 = (R14 - 98.77 + ~18 - ~4.5) / 2
    k0_cvt<<<240, 256, 0, stream>>>(fc1w, fwh, fwl);
    k1_sem<<<1024, 256, 0, stream>>>(x, fwh, fwl, fc1b, u_hi, u_lo);
    k1_sem<<<1024, 256, 0, stream>>>(x, fwh, fwl, fc1b, u_hi, u_lo);
    k1_sem<<<1024, 256, 0, stream>>>(x, fwh, fwl, fc1b, u_hi, u_lo);
    k2_priors<<<1280, 256, 0, stream>>>(u_hi, u_lo, rw, task, part);
    k34_route_out<<<512, 256, 0, stream>>>(part, task, lw, lb, out);
    k34_route_out<<<512, 256, 0, stream>>>(part, task, lw, lb, out);
    k34_route_out<<<512, 256, 0, stream>>>(part, task, lw, lb, out);
}

// Round 15
// 80.712 us; speedup vs baseline: 1.9427x; 1.9427x over previous
//
#include <hip/hip_runtime.h>
#include <hip/hip_bf16.h>

#define Bq 64
#define Sq 256
#define Dq 768
#define CAPq 8
#define NTq 10
#define SCq 2048   // S*CAP

typedef short bf16x8 __attribute__((ext_vector_type(8)));
typedef float f32x4  __attribute__((ext_vector_type(4)));

// split f32 into hi/lo bf16 (bit-truncation; f ~= hi + lo, residual ~2^-17 |f|)
static __device__ __forceinline__ short bfhi(float f) {
    return (short)(__float_as_uint(f) >> 16);
}
static __device__ __forceinline__ short bflo(float f) {
    float hi = __uint_as_float(__float_as_uint(f) & 0xFFFF0000u);
    return (short)(__float_as_uint(f - hi) >> 16);
}
// pack hi/lo bf16 into one uint (hi in high half)
static __device__ __forceinline__ unsigned packhl(float f) {
    unsigned h = __float_as_uint(f) & 0xFFFF0000u;
    float lo = f - __uint_as_float(h);
    return h | (__float_as_uint(lo) >> 16);
}

// ---------------- Kernel 0: preconvert fc1w (80x768 f32, [n*8+c][k]) into
// fragment-major hi/lo bf16: fw2[k/8][col=80][8], col = n*8+c.
__global__ __launch_bounds__(256) void k0_cvt(const float* __restrict__ w,
                                              short* __restrict__ hi,
                                              short* __restrict__ lo) {
    int i = blockIdx.x * 256 + threadIdx.x;   // output index
    if (i < NTq * CAPq * Dq) {
        int k8 = i / 640;
        int rem = i - k8 * 640;
        int o = rem >> 3, kf = rem & 7;
        float f = w[o * Dq + k8 * 8 + kf];
        hi[i] = bfhi(f);
        lo[i] = bflo(f);
    }
}

// ---------------- Kernel 1 (split-bf16 MFMA, LDS-staged x): sem = x·fc1w^T + b,
// squash over routes, write u2i packed (hi<<16|lo) uint, layout [n][s][b][c].
// Block covers a b-PAIR x 8 s (so each (n,s) 64-B line is completed by one block).
__global__ __launch_bounds__(256) void k1_sem(const float* __restrict__ x,
                                              const short* __restrict__ fwh,
                                              const short* __restrict__ fwl,
                                              const float* __restrict__ fc1b,
                                              unsigned* __restrict__ u2i) {
    __shared__ short xsh[12288];   // [k8=96][r16=16][8] hi   (24 KB)
    __shared__ short xsl[12288];   // lo                      (24 KB)
    const int t = threadIdx.x;
    const int L = t & 63, w = t >> 6;          // w = k-part 0..3
    const int colL = L & 15, kg = L >> 4;
    const int bp = blockIdx.x >> 5;            // b-pair: b in {2bp, 2bp+1}
    const int so8 = (blockIdx.x & 31) * 8;     // s in so8..so8+7

    // ---- stage x rows (r16 -> global row (2bp + (r16>>3))*256 + so8 + (r16&7))
#pragma unroll
    for (int i = 0; i < 12; ++i) {
        int li = t + i * 256;                  // float4 index, 0..3071
        int r16 = li / 192, j = li - r16 * 192;
        size_t grow = (size_t)(2 * bp + (r16 >> 3)) * 256 + so8 + (r16 & 7);
        float4 v = *reinterpret_cast<const float4*>(x + grow * Dq + j * 4);
        int k8 = j >> 1, kf = (j & 1) * 4;
        int off = (k8 * 16 + r16) * 8 + kf;
        short4 h4, l4;
        h4.x = bfhi(v.x); h4.y = bfhi(v.y); h4.z = bfhi(v.z); h4.w = bfhi(v.w);
        l4.x = bflo(v.x); l4.y = bflo(v.y); l4.z = bflo(v.z); l4.w = bflo(v.w);
        *reinterpret_cast<short4*>(&xsh[off]) = h4;
        *reinterpret_cast<short4*>(&xsl[off]) = l4;
    }
    __syncthreads();

    f32x4 acc[5];
#pragma unroll
    for (int f = 0; f < 5; ++f) acc[f] = (f32x4){0.f, 0.f, 0.f, 0.f};

    const short* pwh = fwh + kg * 640 + colL * 8;
    const short* pwl = fwl + kg * 640 + colL * 8;

#pragma unroll 2
    for (int kc = 0; kc < 192; kc += 32) {
        const int k8 = ((w * 192 + kc) >> 3) + kg;
        bf16x8 ah = *reinterpret_cast<const bf16x8*>(&xsh[(k8 * 16 + colL) * 8]);
        bf16x8 al = *reinterpret_cast<const bf16x8*>(&xsl[(k8 * 16 + colL) * 8]);
        const int ko80 = (w * 192 + kc) * 80;
#pragma unroll
        for (int f = 0; f < 5; ++f) {
            bf16x8 bh = *reinterpret_cast<const bf16x8*>(pwh + ko80 + f * 128);
            bf16x8 bl = *reinterpret_cast<const bf16x8*>(pwl + ko80 + f * 128);
            acc[f] = __builtin_amdgcn_mfma_f32_16x16x32_bf16(al, bh, acc[f], 0, 0, 0);
            acc[f] = __builtin_amdgcn_mfma_f32_16x16x32_bf16(ah, bl, acc[f], 0, 0, 0);
            acc[f] = __builtin_amdgcn_mfma_f32_16x16x32_bf16(ah, bh, acc[f], 0, 0, 0);
        }
    }

    // ---- 4-way k-reduce: redS overlaid on xsh (all waves done reading xs)
    float* redS = reinterpret_cast<float*>(xsh);   // [3][20][64] floats
    __syncthreads();
    if (w > 0) {
#pragma unroll
        for (int f = 0; f < 5; ++f)
#pragma unroll
            for (int g = 0; g < 4; ++g)
                redS[((w - 1) * 20 + f * 4 + g) * 64 + L] = acc[f][g];
    }
    __syncthreads();
    if (w == 0) {
        float bias[5];
#pragma unroll
        for (int f = 0; f < 5; ++f) bias[f] = fc1b[f * 16 + colL];
        const int cc = colL & 7;
        const int npar = (colL >> 3) & 1;
#pragma unroll
        for (int reg = 0; reg < 4; ++reg) {
            const int r16 = kg * 4 + reg;              // C/D: row=(L>>4)*4+reg
            const int b = 2 * bp + (r16 >> 3);
            const int s = so8 + (r16 & 7);
            float v[5], sqp = 0.f;
#pragma unroll
            for (int f = 0; f < 5; ++f) {
                v[f] = acc[f][reg] + redS[(0 * 20 + f * 4 + reg) * 64 + L]
                     + redS[(1 * 20 + f * 4 + reg) * 64 + L]
                     + redS[(2 * 20 + f * 4 + reg) * 64 + L] + bias[f];
                sqp = fmaf(v[f], v[f], sqp);
            }
            float sq = sqp + __shfl_xor(sqp, 8, 64);   // pair even/odd routes (colL ^ 8)
            float scale = (sq / (1.f + sq)) / sqrtf(sq);
#pragma unroll
            for (int f = 0; f < 5; ++f) {
                int n = 2 * f + npar;
                size_t off = (((size_t)n * 256 + s) * 64 + b) * 8 + cc;   // u2i[n][s][b][c]
                u2i[off] = packhl(v[f] * scale);
            }
        }
    }
}

// ---------------- Kernel 2 (split-bf16 MFMA, LDS-staged rw, raw-barrier async pipeline):
// part[ks][c][b][r][l] = sum_{k in half ks} u[b,r,k]*rw[c,r,k,l]
__global__ __launch_bounds__(256) void k2_priors(const unsigned* __restrict__ u2i,
                                                 const float* __restrict__ rw,
                                                 const int* __restrict__ task_p,
                                                 float* __restrict__ part) {
    const int bid = blockIdx.x;
    const int lq = bid / 160;
    const int rem = bid - lq * 160;          // ks + 2*(r + 10*c)
    const int ks = rem & 1;
    const int rc = rem >> 1;                 // r + 10*c
    const int c = rc / 10;
    const int r = rc - c * 10;
    if (r > *task_p) return;
    __shared__ __attribute__((aligned(16))) float ldsb[2048];   // 2 x [32k][32l] f32
    const int t0 = threadIdx.x;
    const int L = t0 & 63, w = t0 >> 6;
    const int colL = L & 15, kg = L >> 4;
    const int kw0 = ks * 1024;
    const int s00 = ks * 128;

    f32x4 accE = (f32x4){0.f, 0.f, 0.f, 0.f};
    f32x4 accO = (f32x4){0.f, 0.f, 0.f, 0.f};

    const float* psrc = rw + (((size_t)(c * NTq + r)) * SCq + kw0 + w * 8 + (L >> 3)) * Sq
                           + lq * 32 + (L & 7) * 4;
    const unsigned* pui = u2i + (((size_t)r * 256 + s00 + kg) * 64 + w * 16 + colL) * 8;

    float4 stg = *reinterpret_cast<const float4*>(psrc);     // prologue: chunk 0

    for (int t = 0; t < 32; ++t) {
        float* dst = &ldsb[(t & 1) * 1024 + w * 256 + L * 4];
        *reinterpret_cast<float4*>(dst) = stg;
        asm volatile("s_waitcnt lgkmcnt(0)" ::: "memory");
        __builtin_amdgcn_sched_barrier(0);
        __builtin_amdgcn_s_barrier();                        // NO vmcnt drain here
        __builtin_amdgcn_sched_barrier(0);
        // A-loads for chunk t: 32 B contiguous packed (hi<<16|lo)
        uint4 a0 = *reinterpret_cast<const uint4*>(pui + (size_t)t * 2048);
        uint4 a1 = *reinterpret_cast<const uint4*>(pui + (size_t)t * 2048 + 4);
        __builtin_amdgcn_sched_barrier(0);
        if (t + 1 < 32)
            stg = *reinterpret_cast<const float4*>(psrc + (size_t)(t + 1) * 8192);
        __builtin_amdgcn_sched_barrier(0);
        bf16x8 ah, al;
        {
            unsigned uu[8] = {a0.x, a0.y, a0.z, a0.w, a1.x, a1.y, a1.z, a1.w};
#pragma unroll
            for (int i = 0; i < 8; ++i) {
                ah[i] = (short)(uu[i] >> 16);
                al[i] = (short)(uu[i] & 0xFFFFu);
            }
        }
        const float* lbp = &ldsb[(t & 1) * 1024 + colL * 2];
        float2 bv[8];
#pragma unroll
        for (int j = 0; j < 8; ++j)
            bv[j] = *reinterpret_cast<const float2*>(lbp + (kg * 8 + j) * 32);
        bf16x8 bhE, blE, bhO, blO;
#pragma unroll
        for (int j = 0; j < 8; ++j) {
            bhE[j] = bfhi(bv[j].x); blE[j] = bflo(bv[j].x);
            bhO[j] = bfhi(bv[j].y); blO[j] = bflo(bv[j].y);
        }
        accE = __builtin_amdgcn_mfma_f32_16x16x32_bf16(al, bhE, accE, 0, 0, 0);
        accE = __builtin_amdgcn_mfma_f32_16x16x32_bf16(ah, blE, accE, 0, 0, 0);
        accE = __builtin_amdgcn_mfma_f32_16x16x32_bf16(ah, bhE, accE, 0, 0, 0);
        accO = __builtin_amdgcn_mfma_f32_16x16x32_bf16(al, bhO, accO, 0, 0, 0);
        accO = __builtin_amdgcn_mfma_f32_16x16x32_bf16(ah, blO, accO, 0, 0, 0);
        accO = __builtin_amdgcn_mfma_f32_16x16x32_bf16(ah, bhO, accO, 0, 0, 0);
    }

    const int le = lq * 32 + 2 * colL;
#pragma unroll
    for (int g = 0; g < 4; ++g) {
        int bb = w * 16 + kg * 4 + g;
        size_t idx = (size_t)ks * 1310720 + ((size_t)(c * Bq + bb) * NTq + r) * Sq + le;
        float2 vv; vv.x = accE[g]; vv.y = accO[g];
        *reinterpret_cast<float2*>(part + idx) = vv;
    }
}

// ---------------- Kernel 3+4 fused: routing per (c,b) + direct output projection.
// part staged ONCE per block into LDS (kills the 4x redundant global read).
// Lane owns l = lane + 64*ii  ->  conflict-free stride-1 LDS reads, and the
// epilogue extraction is shfl(vote[w], 8j+jj) with one uniform select.
__global__ __launch_bounds__(256) void k34_route_out(const float* __restrict__ part,
                                                     const int* __restrict__ task_p,
                                                     const float* __restrict__ lw,   // [768][8]
                                                     const float* __restrict__ lb,   // [768]
                                                     float* __restrict__ out) {      // [B,S,768]
    __shared__ float prS[NTq][Sq];   // 10 KB
    const int t = threadIdx.x;
    const int lane = t & 63, w = t >> 6;
    const int b = blockIdx.x & 63, c = blockIdx.x >> 6;
    const int task = *task_p;

    // ---- stage pr = part[ks=0] + part[ks=1] into LDS (coalesced, once per block)
    const size_t base = ((size_t)(c * Bq + b) * NTq) * Sq;
#pragma unroll
    for (int r = 0; r < NTq; ++r)
        if (w == (r & 3))   // spread the 10 rows across the 4 waves
            prS[r][ (t & 63) + (r >> 2) * 64 ] = 0.f;  // placeholder (overwritten below)
    // simple full-thread staging: thread t handles column t%256 of each row
#pragma unroll
    for (int r = 0; r < NTq; ++r) {
        float a = part[base + r * Sq + t] + part[1310720 + base + r * Sq + t];
        prS[r][t] = a;
    }
    __syncthreads();

    float pr[NTq][4];
#pragma unroll
    for (int r = 0; r < NTq; ++r)
#pragma unroll
        for (int ii = 0; ii < 4; ++ii) pr[r][ii] = prS[r][lane + 64 * ii];

    float logits[NTq];
#pragma unroll
    for (int r = 0; r < NTq; ++r) logits[r] = 0.f;
    float vote[4];

    for (int it = 0; it < 3; ++it) {
        float m = -1e30f;
#pragma unroll
        for (int r = 0; r < NTq; ++r) if (r <= task) m = fmaxf(m, logits[r]);
        float p[NTq]; float s = 0.f;
#pragma unroll
        for (int r = 0; r < NTq; ++r) {
            p[r] = (r <= task) ? expf(logits[r] - m) : 0.f;
            s += p[r];
        }
        float inv = 1.f / s;
#pragma unroll
        for (int ii = 0; ii < 4; ++ii) vote[ii] = 0.f;
#pragma unroll
        for (int r = 0; r < NTq; ++r) {
            float pw = p[r] * inv;
#pragma unroll
            for (int ii = 0; ii < 4; ++ii) vote[ii] = fmaf(pw, pr[r][ii], vote[ii]);
        }
        if (it == 2) break;

        float vals[11];
#pragma unroll
        for (int r = 0; r < NTq; ++r) {
            float d = 0.f;
#pragma unroll
            for (int ii = 0; ii < 4; ++ii) d = fmaf(pr[r][ii], vote[ii], d);
            vals[r] = d;
        }
        {
            float d = 0.f;
#pragma unroll
            for (int ii = 0; ii < 4; ++ii) d = fmaf(vote[ii], vote[ii], d);
            vals[10] = d;
        }
#pragma unroll
        for (int o = 32; o > 0; o >>= 1) {
#pragma unroll
            for (int v = 0; v < 11; ++v) vals[v] += __shfl_xor(vals[v], o, 64);
        }
        float sq = vals[10];
        float scale = (sq / (1.f + sq)) / sqrtf(sq);
#pragma unroll
        for (int r = 0; r < NTq; ++r)
            if (r <= task) logits[r] += scale * vals[r];
    }

    // ---- epilogue: wave w owns l in [64w, 64w+64) = its own vote component.
    // uniform select of vote[w] (avoid runtime register indexing):
    float vsel = (w == 0) ? vote[0] : (w == 1) ? vote[1] : (w == 2) ? vote[2] : vote[3];
    float v[8][8];
#pragma unroll
    for (int j = 0; j < 8; ++j)
#pragma unroll
        for (int jj = 0; jj < 8; ++jj)
            v[j][jj] = __shfl(vsel, 8 * j + jj, 64);

    const int rbase = c * 2048 + b * 32 + w * 8;
#pragma unroll
    for (int dd = 0; dd < 12; ++dd) {
        int d = lane + dd * 64;
        float4 wa = *reinterpret_cast<const float4*>(lw + (size_t)d * 8);
        float4 wb = *reinterpret_cast<const float4*>(lw + (size_t)d * 8 + 4);
        float lbv = lb[d];
#pragma unroll
        for (int j = 0; j < 8; ++j) {
            float acc = lbv;
            acc = fmaf(v[j][0], wa.x, acc);
            acc = fmaf(v[j][1], wa.y, acc);
            acc = fmaf(v[j][2], wa.z, acc);
            acc = fmaf(v[j][3], wa.w, acc);
            acc = fmaf(v[j][4], wb.x, acc);
            acc = fmaf(v[j][5], wb.y, acc);
            acc = fmaf(v[j][6], wb.z, acc);
            acc = fmaf(v[j][7], wb.w, acc);
            out[(size_t)(rbase + j) * Dq + d] = acc;
        }
    }
}

extern "C" void kernel_launch(void* const* d_in, const int* in_sizes, int n_in,
                              void* d_out, int out_size, void* d_ws, size_t ws_size,
                              hipStream_t stream) {
    const float* x    = (const float*)d_in[0];
    const int*   task = (const int*)d_in[1];
    const float* fc1w = (const float*)d_in[2];
    const float* fc1b = (const float*)d_in[3];
    const float* rw   = (const float*)d_in[4];
    const float* lw   = (const float*)d_in[5];
    const float* lb   = (const float*)d_in[6];
    float* out = (float*)d_out;

    unsigned* u2i = (unsigned*)d_ws;                         // 5,242,880 B (packed hi|lo)
    float* part = (float*)((char*)d_ws + 5242880);           // 10,485,760 B
    short* fwh  = (short*)((char*)d_ws + 16252928);          // 122,880 B
    short* fwl  = fwh + 61440;                               // 122,880 B

    k0_cvt<<<240, 256, 0, stream>>>(fc1w, fwh, fwl);
    k1_sem<<<1024, 256, 0, stream>>>(x, fwh, fwl, fc1b, u2i);
    k2_priors<<<1280, 256, 0, stream>>>(u2i, rw, task, part);
    k34_route_out<<<512, 256, 0, stream>>>(part, task, lw, lb, out);
}

// Round 16
// 68.751 us; speedup vs baseline: 2.2807x; 1.1740x over previous
//
#include <hip/hip_runtime.h>
#include <hip/hip_bf16.h>

#define Bq 64
#define Sq 256
#define Dq 768
#define CAPq 8
#define NTq 10
#define SCq 2048   // S*CAP

typedef short bf16x8 __attribute__((ext_vector_type(8)));
typedef float f32x4  __attribute__((ext_vector_type(4)));

// split f32 into hi/lo bf16 (bit-truncation; f ~= hi + lo, residual ~2^-17 |f|)
static __device__ __forceinline__ short bfhi(float f) {
    return (short)(__float_as_uint(f) >> 16);
}
static __device__ __forceinline__ short bflo(float f) {
    float hi = __uint_as_float(__float_as_uint(f) & 0xFFFF0000u);
    return (short)(__float_as_uint(f - hi) >> 16);
}
// pack hi/lo bf16 into one uint (hi in high half)
static __device__ __forceinline__ unsigned packhl(float f) {
    unsigned h = __float_as_uint(f) & 0xFFFF0000u;
    float lo = f - __uint_as_float(h);
    return h | (__float_as_uint(lo) >> 16);
}

// ---------------- Kernel 0: preconvert fc1w (80x768 f32, [n*8+c][k]) into
// fragment-major hi/lo bf16: fw2[k/8][col=80][8], col = n*8+c.
__global__ __launch_bounds__(256) void k0_cvt(const float* __restrict__ w,
                                              short* __restrict__ hi,
                                              short* __restrict__ lo) {
    int i = blockIdx.x * 256 + threadIdx.x;   // output index
    if (i < NTq * CAPq * Dq) {
        int k8 = i / 640;
        int rem = i - k8 * 640;
        int o = rem >> 3, kf = rem & 7;
        float f = w[o * Dq + k8 * 8 + kf];
        hi[i] = bfhi(f);
        lo[i] = bflo(f);
    }
}

// ---------------- Kernel 1 (split-bf16 MFMA, two-phase 24KB LDS staging):
// sem = x·fc1w^T + b, squash over routes, write u2i packed (hi<<16|lo), [n][s][b][c].
// Block = b-pair x 8 s (16 rows); K staged in two 384-wide phases through ONE
// 24 KB buffer -> 4+ blocks/CU resident (was 3 + tail at 48 KB).
__global__ __launch_bounds__(256) void k1_sem(const float* __restrict__ x,
                                              const short* __restrict__ fwh,
                                              const short* __restrict__ fwl,
                                              const float* __restrict__ fc1b,
                                              unsigned* __restrict__ u2i) {
    __shared__ __attribute__((aligned(16))) char ldsbuf[24576];
    short* xsh = reinterpret_cast<short*>(ldsbuf);          // [k8l=48][r16=16][8] hi (12 KB)
    short* xsl = xsh + 6144;                                // lo (12 KB)
    const int t = threadIdx.x;
    const int L = t & 63, w = t >> 6;          // w = k-subwindow 0..3 within phase
    const int colL = L & 15, kg = L >> 4;
    const int bp = blockIdx.x >> 5;            // b-pair: b in {2bp, 2bp+1}
    const int so8 = (blockIdx.x & 31) * 8;     // s in so8..so8+7

    f32x4 acc[5];
#pragma unroll
    for (int f = 0; f < 5; ++f) acc[f] = (f32x4){0.f, 0.f, 0.f, 0.f};

    const short* pwh = fwh + kg * 640 + colL * 8;
    const short* pwl = fwl + kg * 640 + colL * 8;

#pragma unroll
    for (int p = 0; p < 2; ++p) {
        if (p) __syncthreads();                // previous phase's compute done
        // ---- stage x[16 rows][k in 384p..384p+384) -> LDS hi/lo, coalesced
#pragma unroll
        for (int i = 0; i < 6; ++i) {
            int li = t + i * 256;              // float4 index, 0..1535
            int r16 = li / 96, j = li - r16 * 96;
            size_t grow = (size_t)(2 * bp + (r16 >> 3)) * 256 + so8 + (r16 & 7);
            float4 v = *reinterpret_cast<const float4*>(x + grow * Dq + p * 384 + j * 4);
            int k8l = j >> 1, kf = (j & 1) * 4;
            int off = (k8l * 16 + r16) * 8 + kf;
            short4 h4, l4;
            h4.x = bfhi(v.x); h4.y = bfhi(v.y); h4.z = bfhi(v.z); h4.w = bfhi(v.w);
            l4.x = bflo(v.x); l4.y = bflo(v.y); l4.z = bflo(v.z); l4.w = bflo(v.w);
            *reinterpret_cast<short4*>(&xsh[off]) = h4;
            *reinterpret_cast<short4*>(&xsl[off]) = l4;
        }
        __syncthreads();
        // ---- compute: wave w covers k in [384p + 96w, 384p + 96w + 96)
#pragma unroll
        for (int kc = 0; kc < 96; kc += 32) {
            const int k8l = ((96 * w + kc) >> 3) + kg;
            bf16x8 ah = *reinterpret_cast<const bf16x8*>(&xsh[(k8l * 16 + colL) * 8]);
            bf16x8 al = *reinterpret_cast<const bf16x8*>(&xsl[(k8l * 16 + colL) * 8]);
            const int ko80 = (384 * p + 96 * w + kc) * 80;
#pragma unroll
            for (int f = 0; f < 5; ++f) {
                bf16x8 bh = *reinterpret_cast<const bf16x8*>(pwh + ko80 + f * 128);
                bf16x8 bl = *reinterpret_cast<const bf16x8*>(pwl + ko80 + f * 128);
                acc[f] = __builtin_amdgcn_mfma_f32_16x16x32_bf16(al, bh, acc[f], 0, 0, 0);
                acc[f] = __builtin_amdgcn_mfma_f32_16x16x32_bf16(ah, bl, acc[f], 0, 0, 0);
                acc[f] = __builtin_amdgcn_mfma_f32_16x16x32_bf16(ah, bh, acc[f], 0, 0, 0);
            }
        }
    }

    // ---- 4-way k-reduce: redS overlaid on ldsbuf (15.4 KB <= 24 KB)
    float* redS = reinterpret_cast<float*>(ldsbuf);   // [3][20][64] floats
    __syncthreads();
    if (w > 0) {
#pragma unroll
        for (int f = 0; f < 5; ++f)
#pragma unroll
            for (int g = 0; g < 4; ++g)
                redS[((w - 1) * 20 + f * 4 + g) * 64 + L] = acc[f][g];
    }
    __syncthreads();
    if (w == 0) {
        float bias[5];
#pragma unroll
        for (int f = 0; f < 5; ++f) bias[f] = fc1b[f * 16 + colL];
        const int cc = colL & 7;
        const int npar = (colL >> 3) & 1;
#pragma unroll
        for (int reg = 0; reg < 4; ++reg) {
            const int r16 = kg * 4 + reg;              // C/D: row=(L>>4)*4+reg
            const int b = 2 * bp + (r16 >> 3);
            const int s = so8 + (r16 & 7);
            float v[5], sqp = 0.f;
#pragma unroll
            for (int f = 0; f < 5; ++f) {
                v[f] = acc[f][reg] + redS[(0 * 20 + f * 4 + reg) * 64 + L]
                     + redS[(1 * 20 + f * 4 + reg) * 64 + L]
                     + redS[(2 * 20 + f * 4 + reg) * 64 + L] + bias[f];
                sqp = fmaf(v[f], v[f], sqp);
            }
            float sq = sqp + __shfl_xor(sqp, 8, 64);   // pair even/odd routes (colL ^ 8)
            float scale = (sq / (1.f + sq)) / sqrtf(sq);
#pragma unroll
            for (int f = 0; f < 5; ++f) {
                int n = 2 * f + npar;
                size_t off = (((size_t)n * 256 + s) * 64 + b) * 8 + cc;   // u2i[n][s][b][c]
                u2i[off] = packhl(v[f] * scale);
            }
        }
    }
}

// ---------------- Kernel 2 (split-bf16 MFMA, LDS-staged rw, raw-barrier async pipeline):
// part[ks][c][b][r][l] = sum_{k in half ks} u[b,r,k]*rw[c,r,k,l]
__global__ __launch_bounds__(256) void k2_priors(const unsigned* __restrict__ u2i,
                                                 const float* __restrict__ rw,
                                                 const int* __restrict__ task_p,
                                                 float* __restrict__ part) {
    const int bid = blockIdx.x;
    const int lq = bid / 160;
    const int rem = bid - lq * 160;          // ks + 2*(r + 10*c)
    const int ks = rem & 1;
    const int rc = rem >> 1;                 // r + 10*c
    const int c = rc / 10;
    const int r = rc - c * 10;
    if (r > *task_p) return;
    __shared__ __attribute__((aligned(16))) float ldsb[2048];   // 2 x [32k][32l] f32
    const int t0 = threadIdx.x;
    const int L = t0 & 63, w = t0 >> 6;
    const int colL = L & 15, kg = L >> 4;
    const int kw0 = ks * 1024;
    const int s00 = ks * 128;

    f32x4 accE = (f32x4){0.f, 0.f, 0.f, 0.f};
    f32x4 accO = (f32x4){0.f, 0.f, 0.f, 0.f};

    const float* psrc = rw + (((size_t)(c * NTq + r)) * SCq + kw0 + w * 8 + (L >> 3)) * Sq
                           + lq * 32 + (L & 7) * 4;
    const unsigned* pui = u2i + (((size_t)r * 256 + s00 + kg) * 64 + w * 16 + colL) * 8;

    float4 stg = *reinterpret_cast<const float4*>(psrc);     // prologue: chunk 0

    for (int t = 0; t < 32; ++t) {
        float* dst = &ldsb[(t & 1) * 1024 + w * 256 + L * 4];
        *reinterpret_cast<float4*>(dst) = stg;
        asm volatile("s_waitcnt lgkmcnt(0)" ::: "memory");
        __builtin_amdgcn_sched_barrier(0);
        __builtin_amdgcn_s_barrier();                        // NO vmcnt drain here
        __builtin_amdgcn_sched_barrier(0);
        // A-loads for chunk t: 32 B contiguous packed (hi<<16|lo)
        uint4 a0 = *reinterpret_cast<const uint4*>(pui + (size_t)t * 2048);
        uint4 a1 = *reinterpret_cast<const uint4*>(pui + (size_t)t * 2048 + 4);
        __builtin_amdgcn_sched_barrier(0);
        if (t + 1 < 32)
            stg = *reinterpret_cast<const float4*>(psrc + (size_t)(t + 1) * 8192);
        __builtin_amdgcn_sched_barrier(0);
        bf16x8 ah, al;
        {
            unsigned uu[8] = {a0.x, a0.y, a0.z, a0.w, a1.x, a1.y, a1.z, a1.w};
#pragma unroll
            for (int i = 0; i < 8; ++i) {
                ah[i] = (short)(uu[i] >> 16);
                al[i] = (short)(uu[i] & 0xFFFFu);
            }
        }
        const float* lbp = &ldsb[(t & 1) * 1024 + colL * 2];
        float2 bv[8];
#pragma unroll
        for (int j = 0; j < 8; ++j)
            bv[j] = *reinterpret_cast<const float2*>(lbp + (kg * 8 + j) * 32);
        bf16x8 bhE, blE, bhO, blO;
#pragma unroll
        for (int j = 0; j < 8; ++j) {
            bhE[j] = bfhi(bv[j].x); blE[j] = bflo(bv[j].x);
            bhO[j] = bfhi(bv[j].y); blO[j] = bflo(bv[j].y);
        }
        accE = __builtin_amdgcn_mfma_f32_16x16x32_bf16(al, bhE, accE, 0, 0, 0);
        accE = __builtin_amdgcn_mfma_f32_16x16x32_bf16(ah, blE, accE, 0, 0, 0);
        accE = __builtin_amdgcn_mfma_f32_16x16x32_bf16(ah, bhE, accE, 0, 0, 0);
        accO = __builtin_amdgcn_mfma_f32_16x16x32_bf16(al, bhO, accO, 0, 0, 0);
        accO = __builtin_amdgcn_mfma_f32_16x16x32_bf16(ah, blO, accO, 0, 0, 0);
        accO = __builtin_amdgcn_mfma_f32_16x16x32_bf16(ah, bhO, accO, 0, 0, 0);
    }

    const int le = lq * 32 + 2 * colL;
#pragma unroll
    for (int g = 0; g < 4; ++g) {
        int bb = w * 16 + kg * 4 + g;
        size_t idx = (size_t)ks * 1310720 + ((size_t)(c * Bq + bb) * NTq + r) * Sq + le;
        float2 vv; vv.x = accE[g]; vv.y = accO[g];
        *reinterpret_cast<float2*>(part + idx) = vv;
    }
}

// ---------------- Kernel 3+4 fused: routing per (c,b) + direct output projection.
// part staged ONCE per block into LDS (no redundant global reads, race-free).
__global__ __launch_bounds__(256) void k34_route_out(const float* __restrict__ part,
                                                     const int* __restrict__ task_p,
                                                     const float* __restrict__ lw,   // [768][8]
                                                     const float* __restrict__ lb,   // [768]
                                                     float* __restrict__ out) {      // [B,S,768]
    __shared__ float prS[NTq][Sq];   // 10 KB
    const int t = threadIdx.x;
    const int lane = t & 63, w = t >> 6;
    const int b = blockIdx.x & 63, c = blockIdx.x >> 6;
    const int task = *task_p;

    // ---- stage pr = part[ks=0] + part[ks=1] into LDS (coalesced, once per block)
    const size_t base = ((size_t)(c * Bq + b) * NTq) * Sq;
#pragma unroll
    for (int r = 0; r < NTq; ++r) {
        float a = part[base + r * Sq + t] + part[1310720 + base + r * Sq + t];
        prS[r][t] = a;
    }
    __syncthreads();

    float pr[NTq][4];
#pragma unroll
    for (int r = 0; r < NTq; ++r)
#pragma unroll
        for (int ii = 0; ii < 4; ++ii) pr[r][ii] = prS[r][lane + 64 * ii];

    float logits[NTq];
#pragma unroll
    for (int r = 0; r < NTq; ++r) logits[r] = 0.f;
    float vote[4];

    for (int it = 0; it < 3; ++it) {
        float m = -1e30f;
#pragma unroll
        for (int r = 0; r < NTq; ++r) if (r <= task) m = fmaxf(m, logits[r]);
        float p[NTq]; float s = 0.f;
#pragma unroll
        for (int r = 0; r < NTq; ++r) {
            p[r] = (r <= task) ? expf(logits[r] - m) : 0.f;
            s += p[r];
        }
        float inv = 1.f / s;
#pragma unroll
        for (int ii = 0; ii < 4; ++ii) vote[ii] = 0.f;
#pragma unroll
        for (int r = 0; r < NTq; ++r) {
            float pw = p[r] * inv;
#pragma unroll
            for (int ii = 0; ii < 4; ++ii) vote[ii] = fmaf(pw, pr[r][ii], vote[ii]);
        }
        if (it == 2) break;

        float vals[11];
#pragma unroll
        for (int r = 0; r < NTq; ++r) {
            float d = 0.f;
#pragma unroll
            for (int ii = 0; ii < 4; ++ii) d = fmaf(pr[r][ii], vote[ii], d);
            vals[r] = d;
        }
        {
            float d = 0.f;
#pragma unroll
            for (int ii = 0; ii < 4; ++ii) d = fmaf(vote[ii], vote[ii], d);
            vals[10] = d;
        }
#pragma unroll
        for (int o = 32; o > 0; o >>= 1) {
#pragma unroll
            for (int v = 0; v < 11; ++v) vals[v] += __shfl_xor(vals[v], o, 64);
        }
        float sq = vals[10];
        float scale = (sq / (1.f + sq)) / sqrtf(sq);
#pragma unroll
        for (int r = 0; r < NTq; ++r)
            if (r <= task) logits[r] += scale * vals[r];
    }

    // ---- epilogue: wave w owns l in [64w, 64w+64) = its own vote component.
    float vsel = (w == 0) ? vote[0] : (w == 1) ? vote[1] : (w == 2) ? vote[2] : vote[3];
    float v[8][8];
#pragma unroll
    for (int j = 0; j < 8; ++j)
#pragma unroll
        for (int jj = 0; jj < 8; ++jj)
            v[j][jj] = __shfl(vsel, 8 * j + jj, 64);

    const int rbase = c * 2048 + b * 32 + w * 8;
#pragma unroll
    for (int dd = 0; dd < 12; ++dd) {
        int d = lane + dd * 64;
        float4 wa = *reinterpret_cast<const float4*>(lw + (size_t)d * 8);
        float4 wb = *reinterpret_cast<const float4*>(lw + (size_t)d * 8 + 4);
        float lbv = lb[d];
#pragma unroll
        for (int j = 0; j < 8; ++j) {
            float acc = lbv;
            acc = fmaf(v[j][0], wa.x, acc);
            acc = fmaf(v[j][1], wa.y, acc);
            acc = fmaf(v[j][2], wa.z, acc);
            acc = fmaf(v[j][3], wa.w, acc);
            acc = fmaf(v[j][4], wb.x, acc);
            acc = fmaf(v[j][5], wb.y, acc);
            acc = fmaf(v[j][6], wb.z, acc);
            acc = fmaf(v[j][7], wb.w, acc);
            out[(size_t)(rbase + j) * Dq + d] = acc;
        }
    }
}

extern "C" void kernel_launch(void* const* d_in, const int* in_sizes, int n_in,
                              void* d_out, int out_size, void* d_ws, size_t ws_size,
                              hipStream_t stream) {
    const float* x    = (const float*)d_in[0];
    const int*   task = (const int*)d_in[1];
    const float* fc1w = (const float*)d_in[2];
    const float* fc1b = (const float*)d_in[3];
    const float* rw   = (const float*)d_in[4];
    const float* lw   = (const float*)d_in[5];
    const float* lb   = (const float*)d_in[6];
    float* out = (float*)d_out;

    unsigned* u2i = (unsigned*)d_ws;                         // 5,242,880 B (packed hi|lo)
    float* part = (float*)((char*)d_ws + 5242880);           // 10,485,760 B
    short* fwh  = (short*)((char*)d_ws + 16252928);          // 122,880 B
    short* fwl  = fwh + 61440;                               // 122,880 B

    k0_cvt<<<240, 256, 0, stream>>>(fc1w, fwh, fwl);
    k1_sem<<<1024, 256, 0, stream>>>(x, fwh, fwl, fc1b, u2i);
    k2_priors<<<1280, 256, 0, stream>>>(u2i, rw, task, part);
    k34_route_out<<<512, 256, 0, stream>>>(part, task, lw, lb, out);
}